// Round 6
// baseline (108.428 us; speedup 1.0000x reference)
//
#include <hip/hip_runtime.h>

#define TSTEPS 32
#define HW 65536   // 256*256
#define NB 32
#define N_ELEM (NB * HW)        // 2,097,152
#define N4 (N_ELEM / 4)        // 524,288 float4
#define GRID 1024               // 1024 blocks x 256 thr x 2 float4 = N4
#define CTR 2048                // uint index of barrier counter in ws

// Order-preserving float<->uint key
__device__ __forceinline__ unsigned int f2key(float f) {
    unsigned int u = __float_as_uint(f);
    return (u & 0x80000000u) ? ~u : (u | 0x80000000u);
}
__device__ __forceinline__ float key2f(unsigned int k) {
    unsigned int u = (k & 0x80000000u) ? (k & 0x7fffffffu) : ~k;
    return __uint_as_float(u);
}

__device__ __forceinline__ int spike_t(float x, float mn, float denom, bool valid) {
    // EXACT reference op order: n=(x-mn)/denom ; lat=(1-n)*1.0 ; t=trunc(lat*31)
    float n   = valid ? ((x - mn) / denom) : 0.5f;
    float lat = 1.0f - n;
    int   t   = (int)(lat * 31.0f);       // lat >= 0 so trunc == floor
    t = t < 0 ? 0 : t;
    t = t > (TSTEPS - 1) ? (TSTEPS - 1) : t;
    return t;
}

// Single fused kernel. 1024 blocks co-resident (4 blocks/CU guaranteed by
// __launch_bounds__(256,4): 4096 waves = 4 waves/EU chip-wide).
// Phase 1: per-block min/max partial -> ws[bid], ws[GRID+bid] (pure writes,
//          no init needed). Device-scope release fetch_add on ws[CTR].
// Phase 2: thread0 spins (acquire) until all 1024 partials posted, then the
//          R5-proven 256-thread reduction of the partial arrays.
// Phase 3: R1-proven spike body, inputs already in registers.
__global__ __launch_bounds__(256, 4)
void lc_fused(const float4* __restrict__ in, float* __restrict__ out,
              unsigned int* __restrict__ ws) {
    __shared__ unsigned int smin[4], sinv[4];
    __shared__ float s_mn, s_mx;
    int tid = threadIdx.x;
    int i0  = blockIdx.x * 512 + tid;    // two float4 per thread
    int i1  = i0 + 256;

    float4 v0 = in[i0];
    float4 v1 = in[i1];

    // ---- phase 1: block-local min / inverted-max over 8 floats ----
    unsigned int kmin = 0xFFFFFFFFu, kinv = 0xFFFFFFFFu, k;
    k = f2key(v0.x); kmin = min(kmin, k); kinv = min(kinv, ~k);
    k = f2key(v0.y); kmin = min(kmin, k); kinv = min(kinv, ~k);
    k = f2key(v0.z); kmin = min(kmin, k); kinv = min(kinv, ~k);
    k = f2key(v0.w); kmin = min(kmin, k); kinv = min(kinv, ~k);
    k = f2key(v1.x); kmin = min(kmin, k); kinv = min(kinv, ~k);
    k = f2key(v1.y); kmin = min(kmin, k); kinv = min(kinv, ~k);
    k = f2key(v1.z); kmin = min(kmin, k); kinv = min(kinv, ~k);
    k = f2key(v1.w); kmin = min(kmin, k); kinv = min(kinv, ~k);
    #pragma unroll
    for (int off = 32; off >= 1; off >>= 1) {
        kmin = min(kmin, (unsigned int)__shfl_xor((int)kmin, off, 64));
        kinv = min(kinv, (unsigned int)__shfl_xor((int)kinv, off, 64));
    }
    int wave = tid >> 6;
    if ((tid & 63) == 0) { smin[wave] = kmin; sinv[wave] = kinv; }
    __syncthreads();
    if (tid == 0) {
        #pragma unroll
        for (int w = 1; w < 4; ++w) {
            kmin = min(kmin, smin[w]);
            kinv = min(kinv, sinv[w]);
        }
        ws[blockIdx.x]        = kmin;
        ws[GRID + blockIdx.x] = kinv;
        __threadfence();
        __hip_atomic_fetch_add(&ws[CTR], 1u, __ATOMIC_ACQ_REL,
                               __HIP_MEMORY_SCOPE_AGENT);
        // ---- grid barrier: wait for all 1024 partials ----
        while (__hip_atomic_load(&ws[CTR], __ATOMIC_ACQUIRE,
                                 __HIP_MEMORY_SCOPE_AGENT) < GRID) {
            __builtin_amdgcn_s_sleep(2);
        }
        __threadfence();   // full agent fence: invalidate stale L1/L2 lines
    }
    __syncthreads();

    // ---- phase 2: reduce 1024 partial pairs (L2/L3-hot) ----
    uint4 a = reinterpret_cast<const uint4*>(ws)[tid];
    uint4 c = reinterpret_cast<const uint4*>(ws + GRID)[tid];
    kmin = min(min(a.x, a.y), min(a.z, a.w));
    kinv = min(min(c.x, c.y), min(c.z, c.w));
    #pragma unroll
    for (int off = 32; off >= 1; off >>= 1) {
        kmin = min(kmin, (unsigned int)__shfl_xor((int)kmin, off, 64));
        kinv = min(kinv, (unsigned int)__shfl_xor((int)kinv, off, 64));
    }
    if ((tid & 63) == 0) { smin[wave] = kmin; sinv[wave] = kinv; }
    __syncthreads();
    if (tid == 0) {
        #pragma unroll
        for (int w = 1; w < 4; ++w) {
            kmin = min(kmin, smin[w]);
            kinv = min(kinv, sinv[w]);
        }
        s_mn = key2f(kmin);
        s_mx = key2f(~kinv);
    }
    __syncthreads();

    // ---- phase 3: spike encode + 32-plane coalesced stores (R1 pattern) ----
    float mn = s_mn, mx = s_mx;
    bool  valid = (mx > mn);
    float denom = fmaxf(mx - mn, 1e-12f);

    int t00 = spike_t(v0.x, mn, denom, valid);
    int t01 = spike_t(v0.y, mn, denom, valid);
    int t02 = spike_t(v0.z, mn, denom, valid);
    int t03 = spike_t(v0.w, mn, denom, valid);
    int t10 = spike_t(v1.x, mn, denom, valid);
    int t11 = spike_t(v1.y, mn, denom, valid);
    int t12 = spike_t(v1.z, mn, denom, valid);
    int t13 = spike_t(v1.w, mn, denom, valid);

    // i0, i1 are in the same image (blocks are 512-aligned, HW4=16384)
    int b    = i0 >> 14;
    int rem0 = i0 & 16383;
    int rem1 = i1 & 16383;
    float* base0 = out + (size_t)b * TSTEPS * HW + (size_t)rem0 * 4;
    float* base1 = out + (size_t)b * TSTEPS * HW + (size_t)rem1 * 4;

    #pragma unroll
    for (int tt = 0; tt < TSTEPS; ++tt) {
        float4 o0, o1;
        o0.x = (tt == t00) ? 1.0f : 0.0f;
        o0.y = (tt == t01) ? 1.0f : 0.0f;
        o0.z = (tt == t02) ? 1.0f : 0.0f;
        o0.w = (tt == t03) ? 1.0f : 0.0f;
        o1.x = (tt == t10) ? 1.0f : 0.0f;
        o1.y = (tt == t11) ? 1.0f : 0.0f;
        o1.z = (tt == t12) ? 1.0f : 0.0f;
        o1.w = (tt == t13) ? 1.0f : 0.0f;
        *reinterpret_cast<float4*>(base0 + (size_t)tt * HW) = o0;
        *reinterpret_cast<float4*>(base1 + (size_t)tt * HW) = o1;
    }
}

extern "C" void kernel_launch(void* const* d_in, const int* in_sizes, int n_in,
                              void* d_out, int out_size, void* d_ws, size_t ws_size,
                              hipStream_t stream) {
    const float4*  in = (const float4*)d_in[0];
    float*        out = (float*)d_out;
    unsigned int*  ws = (unsigned int*)d_ws;

    // Zero the barrier counter every call (graph replays the memset node).
    (void)hipMemsetAsync(ws + CTR, 0, sizeof(unsigned int), stream);
    lc_fused<<<GRID, 256, 0, stream>>>(in, out, ws);
}

// Round 8
// 49.783 us; speedup vs baseline: 2.1780x; 2.1780x over previous
//
#include <hip/hip_runtime.h>

#define TSTEPS 32
#define HW 65536    // 256*256
#define HW4 16384   // float4 per plane
#define NB 32
#define N_ELEM (NB * HW)        // 2,097,152
#define N4 (N_ELEM / 4)         // 524,288 float4
#define RED_BLOCKS 1024
#define TOFF 2048               // uint index in ws where t-map begins (8 KB)
#define WS_NEEDED ((TOFF + N4) * sizeof(unsigned int))   // 8KB + 2MB

// Order-preserving float<->uint key
__device__ __forceinline__ unsigned int f2key(float f) {
    unsigned int u = __float_as_uint(f);
    return (u & 0x80000000u) ? ~u : (u | 0x80000000u);
}
__device__ __forceinline__ float key2f(unsigned int k) {
    unsigned int u = (k & 0x80000000u) ? (k & 0x7fffffffu) : ~k;
    return __uint_as_float(u);
}

// K-A: per-block partial min / inverted-max -> ws[bid], ws[RED_BLOCKS+bid].
// Pure writes to distinct slots: no init, no atomics, replay-deterministic.
__global__ void lc_partial(const float4* __restrict__ in, unsigned int* __restrict__ ws) {
    __shared__ unsigned int smin[4], sinv[4];
    int tid = threadIdx.x;
    int i0  = blockIdx.x * 512 + tid;
    unsigned int kmin = 0xFFFFFFFFu, kinv = 0xFFFFFFFFu;
    #pragma unroll
    for (int j = 0; j < 2; ++j) {
        float4 v = in[i0 + j * 256];
        unsigned int k;
        k = f2key(v.x); kmin = min(kmin, k); kinv = min(kinv, ~k);
        k = f2key(v.y); kmin = min(kmin, k); kinv = min(kinv, ~k);
        k = f2key(v.z); kmin = min(kmin, k); kinv = min(kinv, ~k);
        k = f2key(v.w); kmin = min(kmin, k); kinv = min(kinv, ~k);
    }
    #pragma unroll
    for (int off = 32; off >= 1; off >>= 1) {
        kmin = min(kmin, (unsigned int)__shfl_xor((int)kmin, off, 64));
        kinv = min(kinv, (unsigned int)__shfl_xor((int)kinv, off, 64));
    }
    int wave = tid >> 6;
    if ((tid & 63) == 0) { smin[wave] = kmin; sinv[wave] = kinv; }
    __syncthreads();
    if (tid == 0) {
        #pragma unroll
        for (int w = 1; w < 4; ++w) {
            kmin = min(kmin, smin[w]);
            kinv = min(kinv, sinv[w]);
        }
        ws[blockIdx.x]              = kmin;
        ws[RED_BLOCKS + blockIdx.x] = kinv;
    }
}

__device__ __forceinline__ int spike_t(float x, float mn, float denom, bool valid) {
    // EXACT reference op order: n=(x-mn)/denom ; lat=(1-n)*1.0 ; t=trunc(lat*31)
    float n   = valid ? ((x - mn) / denom) : 0.5f;
    float lat = 1.0f - n;
    int   t   = (int)(lat * 31.0f);       // lat >= 0 so trunc == floor
    t = t < 0 ? 0 : t;
    t = t > (TSTEPS - 1) ? (TSTEPS - 1) : t;
    return t;
}

// Shared prologue: reduce the 1024 partial pairs -> (mn, mx) in LDS.
__device__ __forceinline__ void reduce_partials(const unsigned int* __restrict__ ws,
                                                float& mn, float& mx) {
    __shared__ unsigned int smin[4], sinv[4];
    __shared__ float s_mn, s_mx;
    int tid = threadIdx.x;
    uint4 a = reinterpret_cast<const uint4*>(ws)[tid];
    uint4 c = reinterpret_cast<const uint4*>(ws + RED_BLOCKS)[tid];
    unsigned int kmin = min(min(a.x, a.y), min(a.z, a.w));
    unsigned int kinv = min(min(c.x, c.y), min(c.z, c.w));
    #pragma unroll
    for (int off = 32; off >= 1; off >>= 1) {
        kmin = min(kmin, (unsigned int)__shfl_xor((int)kmin, off, 64));
        kinv = min(kinv, (unsigned int)__shfl_xor((int)kinv, off, 64));
    }
    int wave = tid >> 6;
    if ((tid & 63) == 0) { smin[wave] = kmin; sinv[wave] = kinv; }
    __syncthreads();
    if (tid == 0) {
        #pragma unroll
        for (int w = 1; w < 4; ++w) {
            kmin = min(kmin, smin[w]);
            kinv = min(kinv, sinv[w]);
        }
        s_mn = key2f(kmin);
        s_mx = key2f(~kinv);
    }
    __syncthreads();
    mn = s_mn; mx = s_mx;
}

// K-B: finalize min/max, compute per-pixel spike time (0..31), pack 4 per
// uint, write 2 MB t-map to ws+TOFF. 1024 blocks x 256 thr x 2 float4.
__global__ void lc_tmap(const float4* __restrict__ in, unsigned int* __restrict__ ws) {
    float mn, mx;
    reduce_partials(ws, mn, mx);
    bool  valid = (mx > mn);
    float denom = fmaxf(mx - mn, 1e-12f);

    int tid = threadIdx.x;
    int i0  = blockIdx.x * 512 + tid;
    unsigned int* tmap = ws + TOFF;
    #pragma unroll
    for (int j = 0; j < 2; ++j) {
        int i = i0 + j * 256;
        float4 v = in[i];
        unsigned int p =  (unsigned int)spike_t(v.x, mn, denom, valid)
                       | ((unsigned int)spike_t(v.y, mn, denom, valid) << 8)
                       | ((unsigned int)spike_t(v.z, mn, denom, valid) << 16)
                       | ((unsigned int)spike_t(v.w, mn, denom, valid) << 24);
        tmap[i] = p;
    }
}

// K-C: gather. Output written in FLAT SEQUENTIAL order (fill-identical
// stream). 16384 blocks; 16 blocks per plane, each block = 16 KB contiguous
// (256 thr x 4 float4). Reads: 1 uint per output float4 from the 2 MB
// L2-resident t-map.
__global__ void lc_gather(const unsigned int* __restrict__ ws, float4* __restrict__ out) {
    const unsigned int* tmap = ws + TOFF;
    int blk   = blockIdx.x;          // 0..16383
    int plane = blk >> 4;            // 0..1023 = b*TSTEPS + tt
    unsigned int tt = (unsigned int)(plane & 31);
    int b     = plane >> 5;
    int base4 = (blk & 15) * 1024 + threadIdx.x;   // f4 idx within plane
    const unsigned int* tp = tmap + b * HW4;
    float4* op = out + (size_t)plane * HW4;
    #pragma unroll
    for (int j = 0; j < 4; ++j) {
        int h = base4 + j * 256;
        unsigned int tw = tp[h];
        float4 o;
        o.x = (( tw        & 255u) == tt) ? 1.0f : 0.0f;
        o.y = (((tw >> 8)  & 255u) == tt) ? 1.0f : 0.0f;
        o.z = (((tw >> 16) & 255u) == tt) ? 1.0f : 0.0f;
        o.w = (( tw >> 24        ) == tt) ? 1.0f : 0.0f;
        op[h] = o;
    }
}

// Fallback scatter spike (R5-proven, used only if ws is too small for t-map).
__global__ void lc_spike(const float4* __restrict__ in, float* __restrict__ out,
                         const unsigned int* __restrict__ ws) {
    float mn, mx;
    reduce_partials(ws, mn, mx);
    bool  valid = (mx > mn);
    float denom = fmaxf(mx - mn, 1e-12f);

    int idx = blockIdx.x * blockDim.x + threadIdx.x;
    int b   = idx >> 14;
    int rem = idx & 16383;

    float4 v = in[idx];
    int t0 = spike_t(v.x, mn, denom, valid);
    int t1 = spike_t(v.y, mn, denom, valid);
    int t2 = spike_t(v.z, mn, denom, valid);
    int t3 = spike_t(v.w, mn, denom, valid);

    float* base = out + (size_t)b * TSTEPS * HW + (size_t)rem * 4;
    #pragma unroll
    for (int tt = 0; tt < TSTEPS; ++tt) {
        float4 o;
        o.x = (tt == t0) ? 1.0f : 0.0f;
        o.y = (tt == t1) ? 1.0f : 0.0f;
        o.z = (tt == t2) ? 1.0f : 0.0f;
        o.w = (tt == t3) ? 1.0f : 0.0f;
        *reinterpret_cast<float4*>(base + (size_t)tt * HW) = o;
    }
}

extern "C" void kernel_launch(void* const* d_in, const int* in_sizes, int n_in,
                              void* d_out, int out_size, void* d_ws, size_t ws_size,
                              hipStream_t stream) {
    const float4*  in = (const float4*)d_in[0];
    unsigned int*  ws = (unsigned int*)d_ws;

    lc_partial<<<RED_BLOCKS, 256, 0, stream>>>(in, ws);
    if (ws_size >= WS_NEEDED) {
        lc_tmap<<<RED_BLOCKS, 256, 0, stream>>>(in, ws);
        lc_gather<<<NB * TSTEPS * 16, 256, 0, stream>>>(ws, (float4*)d_out);
    } else {
        lc_spike<<<N4 / 256, 256, 0, stream>>>(in, (float*)d_out, ws);
    }
}

// Round 9
// 48.029 us; speedup vs baseline: 2.2575x; 1.0365x over previous
//
#include <hip/hip_runtime.h>

#define TSTEPS 32
#define HW 65536   // 256*256
#define NB 32
#define N_ELEM (NB * HW)        // 2,097,152
#define N4 (N_ELEM / 4)         // 524,288
#define RED_BLOCKS 1024         // partial-reduction blocks

// Order-preserving float<->uint key (works for all floats incl. negatives)
__device__ __forceinline__ unsigned int f2key(float f) {
    unsigned int u = __float_as_uint(f);
    return (u & 0x80000000u) ? ~u : (u | 0x80000000u);
}
__device__ __forceinline__ float key2f(unsigned int k) {
    unsigned int u = (k & 0x80000000u) ? (k & 0x7fffffffu) : ~k;
    return __uint_as_float(u);
}

// K1: per-block partial min/inv-max keys -> ws[bid] (min), ws[RED_BLOCKS+bid]
// (inverted max). Pure writes to distinct slots: no init, no atomics,
// deterministic across graph replays.
__global__ void lc_partial(const float4* __restrict__ in, unsigned int* __restrict__ ws) {
    __shared__ unsigned int smin[4], sinv[4];
    int tid = threadIdx.x;
    int i0  = blockIdx.x * 512 + tid;     // two float4 per thread: i0, i0+256
    unsigned int kmin = 0xFFFFFFFFu, kinv = 0xFFFFFFFFu;
    #pragma unroll
    for (int j = 0; j < 2; ++j) {
        float4 v = in[i0 + j * 256];
        unsigned int k;
        k = f2key(v.x); kmin = min(kmin, k); kinv = min(kinv, ~k);
        k = f2key(v.y); kmin = min(kmin, k); kinv = min(kinv, ~k);
        k = f2key(v.z); kmin = min(kmin, k); kinv = min(kinv, ~k);
        k = f2key(v.w); kmin = min(kmin, k); kinv = min(kinv, ~k);
    }
    #pragma unroll
    for (int off = 32; off >= 1; off >>= 1) {
        kmin = min(kmin, (unsigned int)__shfl_xor((int)kmin, off, 64));
        kinv = min(kinv, (unsigned int)__shfl_xor((int)kinv, off, 64));
    }
    int wave = tid >> 6;
    if ((tid & 63) == 0) { smin[wave] = kmin; sinv[wave] = kinv; }
    __syncthreads();
    if (tid == 0) {
        #pragma unroll
        for (int w = 1; w < 4; ++w) {
            kmin = min(kmin, smin[w]);
            kinv = min(kinv, sinv[w]);
        }
        ws[blockIdx.x]              = kmin;
        ws[RED_BLOCKS + blockIdx.x] = kinv;
    }
}

__device__ __forceinline__ int spike_t(float x, float mn, float denom, bool valid) {
    // EXACT reference op order: n=(x-mn)/denom ; lat=(1-n)*1.0 ; t=trunc(lat*31)
    float n   = valid ? ((x - mn) / denom) : 0.5f;
    float lat = 1.0f - n;                 // * MAX_LATENCY(=1.0) is exact
    int   t   = (int)(lat * 31.0f);       // lat >= 0 so trunc == floor
    t = t < 0 ? 0 : t;
    t = t > (TSTEPS - 1) ? (TSTEPS - 1) : t;
    return t;
}

// K2: prologue reduces the 1024 partial pairs (8 KB, L2-hot), then the
// R1-measured spike body: thread = one float4 column, 32 coalesced plane
// stores (64 lanes x 16B = 1KB per instruction).
__global__ void lc_spike(const float4* __restrict__ in, float* __restrict__ out,
                         const unsigned int* __restrict__ ws) {
    __shared__ unsigned int smin[4], sinv[4];
    __shared__ float s_mn, s_mx;
    int tid = threadIdx.x;

    // each thread loads 4 min-keys and 4 inv-keys (256 threads x 4 = 1024)
    uint4 a = reinterpret_cast<const uint4*>(ws)[tid];
    uint4 c = reinterpret_cast<const uint4*>(ws + RED_BLOCKS)[tid];
    unsigned int kmin = min(min(a.x, a.y), min(a.z, a.w));
    unsigned int kinv = min(min(c.x, c.y), min(c.z, c.w));
    #pragma unroll
    for (int off = 32; off >= 1; off >>= 1) {
        kmin = min(kmin, (unsigned int)__shfl_xor((int)kmin, off, 64));
        kinv = min(kinv, (unsigned int)__shfl_xor((int)kinv, off, 64));
    }
    int wave = tid >> 6;
    if ((tid & 63) == 0) { smin[wave] = kmin; sinv[wave] = kinv; }
    __syncthreads();
    if (tid == 0) {
        #pragma unroll
        for (int w = 1; w < 4; ++w) {
            kmin = min(kmin, smin[w]);
            kinv = min(kinv, sinv[w]);
        }
        s_mn = key2f(kmin);
        s_mx = key2f(~kinv);
    }
    __syncthreads();

    float mn = s_mn, mx = s_mx;
    bool  valid = (mx > mn);
    float denom = fmaxf(mx - mn, 1e-12f);

    int idx = blockIdx.x * blockDim.x + tid;   // 0 .. N4-1
    int b   = idx >> 14;          // idx / (HW/4)
    int rem = idx & 16383;        // idx % (HW/4)

    float4 v = in[idx];
    int t0 = spike_t(v.x, mn, denom, valid);
    int t1 = spike_t(v.y, mn, denom, valid);
    int t2 = spike_t(v.z, mn, denom, valid);
    int t3 = spike_t(v.w, mn, denom, valid);

    float* base = out + (size_t)b * TSTEPS * HW + (size_t)rem * 4;
    #pragma unroll
    for (int tt = 0; tt < TSTEPS; ++tt) {
        float4 o;
        o.x = (tt == t0) ? 1.0f : 0.0f;
        o.y = (tt == t1) ? 1.0f : 0.0f;
        o.z = (tt == t2) ? 1.0f : 0.0f;
        o.w = (tt == t3) ? 1.0f : 0.0f;
        *reinterpret_cast<float4*>(base + (size_t)tt * HW) = o;
    }
}

extern "C" void kernel_launch(void* const* d_in, const int* in_sizes, int n_in,
                              void* d_out, int out_size, void* d_ws, size_t ws_size,
                              hipStream_t stream) {
    const float4*  in = (const float4*)d_in[0];
    float*        out = (float*)d_out;
    unsigned int*  ws = (unsigned int*)d_ws;

    lc_partial<<<RED_BLOCKS, 256, 0, stream>>>(in, ws);
    lc_spike<<<N4 / 256, 256, 0, stream>>>(in, out, ws);
}